// Round 4
// baseline (446.160 us; speedup 1.0000x reference)
//
#include <hip/hip_runtime.h>
#include <stdint.h>

typedef float f32x4 __attribute__((ext_vector_type(4)));
typedef short s16x8 __attribute__((ext_vector_type(8)));
typedef short s16x4 __attribute__((ext_vector_type(4)));

__device__ __forceinline__ short f2bf(float f){
  union { float f; unsigned u; } v; v.f = f;
  unsigned r = v.u + 0x7FFFu + ((v.u >> 16) & 1u);
  return (short)(r >> 16);
}
__device__ __forceinline__ float bf2f(short h){
  union { unsigned u; float f; } v; v.u = ((unsigned)(unsigned short)h) << 16;
  return v.f;
}

// ---------- elementwise: o = bf16(a+b), 8 elems/thread ----------
__global__ void k_addcvt(const float* __restrict__ a, const float* __restrict__ b,
                         short* __restrict__ o){
  long i = (long)blockIdx.x * blockDim.x + threadIdx.x;
  const f32x4* a4 = (const f32x4*)a;
  const f32x4* b4 = (const f32x4*)b;
  f32x4 x0 = a4[2*i], x1 = a4[2*i+1];
  f32x4 y0 = b4[2*i], y1 = b4[2*i+1];
  s16x8 r;
  #pragma unroll
  for (int j=0;j<4;j++){ r[j] = f2bf(x0[j]+y0[j]); r[j+4] = f2bf(x1[j]+y1[j]); }
  *(s16x8*)(o + i*8) = r;
}

// ---------- fp32 -> bf16 convert, 3 tensors in one launch ----------
__global__ void k_cvt3(const float* __restrict__ s0, short* __restrict__ d0,
                       const float* __restrict__ s1, short* __restrict__ d1,
                       const float* __restrict__ s2, short* __restrict__ d2){
  int z = blockIdx.y;
  const float* in = (z==0) ? s0 : ((z==1) ? s1 : s2);
  short* out      = (z==0) ? d0 : ((z==1) ? d1 : d2);
  long i = (long)blockIdx.x * blockDim.x + threadIdx.x;
  f32x4 v = ((const f32x4*)in)[i];
  s16x4 r;
  #pragma unroll
  for (int j=0;j<4;j++) r[j] = f2bf(v[j]);
  *(s16x4*)(out + i*4) = r;
}

// ---------- transpose + convert, 3 tensors (1024x1024 each) ----------
__global__ void k_transcvt3(const float* __restrict__ s0, short* __restrict__ d0,
                            const float* __restrict__ s1, short* __restrict__ d1,
                            const float* __restrict__ s2, short* __restrict__ d2){
  int z = blockIdx.z;
  const float* in = (z==0) ? s0 : ((z==1) ? s1 : s2);
  short* out      = (z==0) ? d0 : ((z==1) ? d1 : d2);
  __shared__ float tile[32][33];
  int c0 = blockIdx.x*32, r0 = blockIdx.y*32;
  #pragma unroll
  for (int i=threadIdx.y; i<32; i+=8)
    tile[i][threadIdx.x] = in[(long)(r0+i)*1024 + c0 + threadIdx.x];
  __syncthreads();
  #pragma unroll
  for (int i=threadIdx.y; i<32; i+=8)
    out[(long)(c0+i)*1024 + r0 + threadIdx.x] = f2bf(tile[threadIdx.x][i]);
}

// ---------- bias1 ----------
__global__ void k_bias1(const float* __restrict__ wt, const float* __restrict__ bvt, const float* __restrict__ obt,
                        const float* __restrict__ wi, const float* __restrict__ bvi, const float* __restrict__ obi,
                        float* __restrict__ bc){
  int z = blockIdx.y;
  const float* w  = z ? wi  : wt;
  const float* bv = z ? bvi : bvt;
  const float* ob = z ? obi : obt;
  int n = blockIdx.x*4 + (threadIdx.x>>6);
  int lane = threadIdx.x & 63;
  const float* row = w + (long)n*1024;
  float acc = 0.f;
  for (int j=lane; j<1024; j+=64) acc += row[j]*bv[j];
  #pragma unroll
  for (int m=32;m;m>>=1) acc += __shfl_xor(acc, m, 64);
  if (lane==0) bc[z*1024+n] = acc + ob[n];
}

// ---------- bias2 + fuse_b copy folded in (blocks 512..515 copy) ----------
__global__ void k_bias2c(const short* __restrict__ Wc, const float* __restrict__ fuse_b,
                         const float* __restrict__ bc, float* __restrict__ b_all){
  if (blockIdx.x >= 512) {
    int i = (blockIdx.x - 512)*256 + threadIdx.x;
    b_all[i] = fuse_b[i];
    return;
  }
  int n = blockIdx.x*4 + (threadIdx.x>>6);
  int lane = threadIdx.x & 63;
  const short* row = Wc + (long)n*1024;
  float acc = 0.f;
  for (int j=lane; j<1024; j+=64) acc += bf2f(row[j])*fuse_b[j];
  #pragma unroll
  for (int m=32;m;m>>=1) acc += __shfl_xor(acc, m, 64);
  if (lane==0) b_all[1024+n] = acc + bc[n];
}

#define GLDS(src, dst) __builtin_amdgcn_global_load_lds( \
    (const __attribute__((address_space(1))) void*)(src), \
    (__attribute__((address_space(3))) void*)(dst), 16, 0, 0)

// ---------- small NT GEMM (128x128 tile, m97 structure): C bf16 = A@B^T ----------
__global__ __launch_bounds__(256, 2)
void gemm_nt_small(const short* __restrict__ Abase, const short* __restrict__ Bbase,
                   short* __restrict__ Cbase,
                   int M, int N, int K, long zA, long zB, long zC)
{
  __shared__ __align__(16) short ldsA[128*32];
  __shared__ __align__(16) short ldsB[128*32];
  const short* A = Abase + (long)blockIdx.z * zA;
  const short* B = Bbase + (long)blockIdx.z * zB;
  const int m0 = blockIdx.x * 128;
  const int n0 = blockIdx.y * 128;
  const int tid = threadIdx.x;
  const int lane = tid & 63;
  const int wv = tid >> 6;
  const int wm = wv >> 1, wn = wv & 1;

  f32x4 acc[4][4];
  #pragma unroll
  for (int i=0;i<4;i++)
    #pragma unroll
    for (int j=0;j<4;j++) acc[i][j] = (f32x4){0.f,0.f,0.f,0.f};

  const int bo0 = wv*1024 + lane*16;
  const int bo1 = bo0 + 4096;
  const int r0 = bo0 >> 6, c0 = bo0 & 63;
  const int r1 = bo1 >> 6, c1 = bo1 & 63;
  const long rsb = (long)K * 2;

  const char* Ab = (const char*)A;
  const char* Bb = (const char*)B;
  char* lA = (char*)&ldsA[0];
  char* lB = (char*)&ldsB[0];

  const int nkt = K >> 5;
  for (int kt = 0; kt < nkt; ++kt) {
    const long kb = (long)kt * 64;
    GLDS(Ab + (long)(m0 + r0)*rsb + kb + c0, lA + wv*1024);
    GLDS(Ab + (long)(m0 + r1)*rsb + kb + c1, lA + 4096 + wv*1024);
    GLDS(Bb + (long)(n0 + r0)*rsb + kb + c0, lB + wv*1024);
    GLDS(Bb + (long)(n0 + r1)*rsb + kb + c1, lB + 4096 + wv*1024);
    __syncthreads();

    s16x8 af[4], bfv[4];
    #pragma unroll
    for (int i=0;i<4;i++)
      af[i] = *(const s16x8*)(lA + (wm*64 + i*16 + (lane&15))*64 + (lane>>4)*16);
    #pragma unroll
    for (int j=0;j<4;j++)
      bfv[j] = *(const s16x8*)(lB + (wn*64 + j*16 + (lane&15))*64 + (lane>>4)*16);

    #pragma unroll
    for (int i=0;i<4;i++)
      #pragma unroll
      for (int j=0;j<4;j++)
        acc[i][j] = __builtin_amdgcn_mfma_f32_16x16x32_bf16(af[i], bfv[j], acc[i][j], 0, 0, 0);
    __syncthreads();
  }

  short* C = Cbase + (long)blockIdx.z * zC;
  #pragma unroll
  for (int j=0;j<4;j++){
    int gn = n0 + wn*64 + j*16 + (lane&15);
    #pragma unroll
    for (int i=0;i<4;i++){
      int gmb = m0 + wm*64 + i*16 + ((lane>>4)*4);
      #pragma unroll
      for (int r=0;r<4;r++)
        C[(long)(gmb+r)*N + gn] = f2bf(acc[i][j][r]);
    }
  }
}

// ---------- main NT GEMM: 256x256, BK=64, 8-phase, PIPELINED frag reads ----------
// LDS: A-buf0 @0, A-buf1 @32768, B-buf0 @65536, B-buf1 @98304.
// Swizzle: chunk s of row r stored at s^(r&7) (conflict-free; verified R3).
// Each phase: issue NEXT phase's ds_reads + stage slot BEFORE the barrier; MFMA
// (using frags read one phase earlier) AFTER. No lgkmcnt(0): compiler emits
// precise per-register waits, so next-phase reads stay outstanding under MFMA.
// Slots/iter (tiles t,t+1; afP/afQ = A-frag banks; bfr0/bfr1 = B-frag banks):
//  ph1: rd A0 i23          stg A(t+1)H0->A1
//  ph2: rd A0 i45          stg A(t+1)H1->A1 + B(t+2)H0->B0
//  ph3: rd A0 i67          stg B(t+2)H1->B0, VMW4 (drain prev-B + A(t+1))
//  ph4: rd A1 i01 + bfr1   (A1,B1 sync'd by ph3 VMW4+barrier)
//  ph5-7: mirror (stg A(t+2)->A0, B(t+3)->B1, VMW4 @ph7)
//  ph8: rd A0 i01(t+2) + bfr0(t+2)
#define MFMA16 __builtin_amdgcn_mfma_f32_16x16x32_bf16
#define VMW4 asm volatile("s_waitcnt vmcnt(4)" ::: "memory")
#define VMW0 asm volatile("s_waitcnt vmcnt(0)" ::: "memory")
#define NOP ((void)0)

#define LDBF0 { _Pragma("unroll") for (int j=0;j<4;j++){ bfr0[j][0]=ldB(0,j,0); bfr0[j][1]=ldB(0,j,1);} }
#define LDBF1 { _Pragma("unroll") for (int j=0;j<4;j++){ bfr1[j][0]=ldB(1,j,0); bfr1[j][1]=ldB(1,j,1);} }

#define PH(ACC0, AC, AN, NBUF, NQ, BF, LDBF, STAGE_STMT, VM) { \
  AN[0] = ldA(NBUF, 2*(NQ),   0); \
  AN[1] = ldA(NBUF, 2*(NQ),   1); \
  AN[2] = ldA(NBUF, 2*(NQ)+1, 0); \
  AN[3] = ldA(NBUF, 2*(NQ)+1, 1); \
  LDBF; \
  STAGE_STMT; \
  VM; \
  asm volatile("" ::: "memory"); \
  __builtin_amdgcn_s_barrier(); \
  __builtin_amdgcn_s_setprio(1); \
  _Pragma("unroll") \
  for (int j=0;j<4;j++){ \
    acc[(ACC0)][j]   = MFMA16(AC[0], BF[j][0], acc[(ACC0)][j],   0,0,0); \
    acc[(ACC0)][j]   = MFMA16(AC[1], BF[j][1], acc[(ACC0)][j],   0,0,0); \
    acc[(ACC0)+1][j] = MFMA16(AC[2], BF[j][0], acc[(ACC0)+1][j], 0,0,0); \
    acc[(ACC0)+1][j] = MFMA16(AC[3], BF[j][1], acc[(ACC0)+1][j], 0,0,0); \
  } \
  __builtin_amdgcn_s_setprio(0); \
}

__global__ __launch_bounds__(512, 2)
void gemm_main(const short* __restrict__ A, const short* __restrict__ B,
               float* __restrict__ O, const float* __restrict__ bias,
               int M, int N, int K)
{
  __shared__ __align__(16) char lds[131072];

  const int nbn = N >> 8;
  const int nwg = (M >> 8) * nbn;
  const int cpx = nwg >> 3;
  int bid = blockIdx.x;
  int swz = (bid & 7) * cpx + (bid >> 3);
  const int m0 = (swz / nbn) << 8;
  const int n0 = (swz % nbn) << 8;

  const int tid  = threadIdx.x;
  const int lane = tid & 63;
  const int wid  = tid >> 6;
  const int wm   = wid >> 2;   // 0..1
  const int wn   = wid & 3;    // 0..3
  const long rsb = (long)K * 2;
  const char* Ab = (const char*)A;
  const char* Bb = (const char*)B;

  f32x4 acc[8][4];
  #pragma unroll
  for (int i=0;i<8;i++)
    #pragma unroll
    for (int j=0;j<4;j++) acc[i][j] = (f32x4){0.f,0.f,0.f,0.f};

  // Stage source precompute: linear LDS dest chunk c receives logical chunk
  // q = c ^ ((c>>3)&7)  (row preserved; inverse of the read swizzle).
  long srow[2][2]; int scol[2][2]; int sdst[2][2];
  #pragma unroll
  for (int H=0;H<2;H++)
    #pragma unroll
    for (int sb=0;sb<2;sb++){
      int c = H*1024 + sb*512 + wid*64 + lane;
      int q = c ^ ((c>>3)&7);
      srow[H][sb] = (long)(q >> 3);
      scol[H][sb] = (q & 7) << 4;
      sdst[H][sb] = (H*1024 + sb*512 + wid*64) << 4;
    }

  auto stage = [&](const char* P, int tr0, int s /*K-tile*/, int RB, int H){
    const long ktb = (long)s << 7;
    GLDS(P + ((long)tr0 + srow[H][0])*rsb + ktb + scol[H][0], lds + RB + sdst[H][0]);
    GLDS(P + ((long)tr0 + srow[H][1])*rsb + ktb + scol[H][1], lds + RB + sdst[H][1]);
  };

  const int swx = (lane & 7) << 4;   // read swizzle (row&7 == lane&7 for all frags)
  auto ldA = [&](int buf, int i, int ks) -> s16x8 {
    int off = (wm*128 + i*16 + (lane&15))*128 + ks*64 + ((lane>>4)<<4);
    off ^= swx;
    return *(const s16x8*)(lds + (buf<<15) + off);
  };
  auto ldB = [&](int buf, int j, int ks) -> s16x8 {
    int off = (wn*64 + j*16 + (lane&15))*128 + ks*64 + ((lane>>4)<<4);
    off ^= swx;
    return *(const s16x8*)(lds + 65536 + (buf<<15) + off);
  };

  s16x8 bfr0[4][2], bfr1[4][2];
  s16x8 afP[4], afQ[4];
  const int nkt = K >> 6;  // 64-wide K-tiles (even, >= 4)

  // Prologue: A(0)->A0, B(0)->B0, B(1)->B1; drain A(0),B(0); keep B(1) in flight.
  stage(Ab, m0, 0, 0,     0); stage(Ab, m0, 0, 0,     1);
  stage(Bb, n0, 0, 65536, 0); stage(Bb, n0, 0, 65536, 1);
  stage(Bb, n0, 1, 98304, 0); stage(Bb, n0, 1, 98304, 1);
  VMW4;
  asm volatile("" ::: "memory");
  __builtin_amdgcn_s_barrier();
  // Preload frags for ph1 (consumed after next barrier; lgkm tracked by compiler).
  LDBF0;
  afP[0]=ldA(0,0,0); afP[1]=ldA(0,0,1); afP[2]=ldA(0,1,0); afP[3]=ldA(0,1,1);

  for (int it = 0; it < (nkt>>1) - 1; ++it) {
    const int t = it*2;
    PH(0, afP, afQ, 0, 1, bfr0, NOP, stage(Ab, m0, t+1, 32768, 0), NOP)
    PH(2, afQ, afP, 0, 2, bfr0, NOP, (stage(Ab, m0, t+1, 32768, 1), stage(Bb, n0, t+2, 65536, 0)), NOP)
    PH(4, afP, afQ, 0, 3, bfr0, NOP, stage(Bb, n0, t+2, 65536, 1), VMW4)
    PH(6, afQ, afP, 1, 0, bfr0, LDBF1, NOP, NOP)
    PH(0, afP, afQ, 1, 1, bfr1, NOP, stage(Ab, m0, t+2, 0, 0), NOP)
    PH(2, afQ, afP, 1, 2, bfr1, NOP, (stage(Ab, m0, t+2, 0, 1), stage(Bb, n0, t+3, 98304, 0)), NOP)
    PH(4, afP, afQ, 1, 3, bfr1, NOP, stage(Bb, n0, t+3, 98304, 1), VMW4)
    PH(6, afQ, afP, 0, 0, bfr1, LDBF0, NOP, NOP)
  }
  {
    // Final iter (t = nkt-2): stage only A(nkt-1); VMW0 at ph3; ph8 reads are dead (DCE'd).
    PH(0, afP, afQ, 0, 1, bfr0, NOP, stage(Ab, m0, nkt-1, 32768, 0), NOP)
    PH(2, afQ, afP, 0, 2, bfr0, NOP, stage(Ab, m0, nkt-1, 32768, 1), NOP)
    PH(4, afP, afQ, 0, 3, bfr0, NOP, NOP, VMW0)
    PH(6, afQ, afP, 1, 0, bfr0, LDBF1, NOP, NOP)
    PH(0, afP, afQ, 1, 1, bfr1, NOP, NOP, NOP)
    PH(2, afQ, afP, 1, 2, bfr1, NOP, NOP, NOP)
    PH(4, afP, afQ, 1, 3, bfr1, NOP, NOP, NOP)
    PH(6, afQ, afP, 0, 0, bfr1, NOP, NOP, NOP)
  }

  // Epilogue: fp32 + bias, scatter by output region (text | image | fused).
  const long BD = (long)M * 1024L;
  #pragma unroll
  for (int j=0;j<4;j++){
    int gn = n0 + wn*64 + j*16 + (lane&15);
    float bb = bias[gn];
    int region = gn >> 10;
    long rbase = (region==0) ? 2*BD : ((region==1) ? 0L : BD);
    int col = gn & 1023;
    #pragma unroll
    for (int i=0;i<8;i++){
      int gr = m0 + wm*128 + i*16 + ((lane>>4)<<2);
      #pragma unroll
      for (int r=0;r<4;r++)
        O[rbase + (long)(gr+r)*1024 + col] = acc[i][j][r] + bb;
    }
  }
}

extern "C" void kernel_launch(void* const* d_in, const int* in_sizes, int n_in,
                              void* d_out, int out_size, void* d_ws, size_t ws_size,
                              hipStream_t stream) {
  const float* text    = (const float*)d_in[0];
  const float* image   = (const float*)d_in[1];
  const float* fuse_w  = (const float*)d_in[2];
  const float* fuse_b  = (const float*)d_in[3];
  const float* t_in_w  = (const float*)d_in[4];
  const float* t_in_b  = (const float*)d_in[5];
  const float* t_out_w = (const float*)d_in[6];
  const float* t_out_b = (const float*)d_in[7];
  const float* i_in_w  = (const float*)d_in[8];
  const float* i_in_b  = (const float*)d_in[9];
  const float* i_out_w = (const float*)d_in[10];
  const float* i_out_b = (const float*)d_in[11];
  float* out = (float*)d_out;

  const long DD = 1024L*1024L;
  char* ws = (char*)d_ws;
  short* s_bf    = (short*)ws; ws += 16384L*1024*2;
  short* W_all   = (short*)ws; ws += 3*DD*2;      // rows: [fuse_w; Wt2; Wi2]
  short* wvT     = (short*)ws; ws += 2*DD*2;      // [wvT_t; wvT_i]
  short* fuse_wT = (short*)ws; ws += DD*2;
  short* outw_st = (short*)ws; ws += 2*DD*2;      // [t_out_w; i_out_w] bf16
  short* Wc_st   = (short*)ws; ws += 2*DD*2;      // [Wc_t; Wc_i]
  float* bc      = (float*)ws; ws += 2048*4;
  float* b_all   = (float*)ws; ws += 3072*4;

  // prep
  k_addcvt<<<8192, 256, 0, stream>>>(text, image, s_bf);
  k_cvt3<<<dim3(1024,3), 256, 0, stream>>>(fuse_w, W_all,
                                           t_out_w, outw_st,
                                           i_out_w, outw_st + DD);
  k_transcvt3<<<dim3(32,32,3), dim3(32,8), 0, stream>>>(t_in_w + 2*DD, wvT,
                                                        i_in_w + 2*DD, wvT + DD,
                                                        fuse_w, fuse_wT);
  k_bias1<<<dim3(256,2), 256, 0, stream>>>(t_out_w, t_in_b + 2048, t_out_b,
                                           i_out_w, i_in_b + 2048, i_out_b, bc);

  // Wc_z = out_w_z @ wv_z
  gemm_nt_small<<<dim3(8,8,2), 256, 0, stream>>>(outw_st, wvT, Wc_st,
                                                 1024, 1024, 1024, DD, DD, DD);
  // b_all[1024..3072) = Wc @ fuse_b + bc ; b_all[0..1024) = fuse_b
  k_bias2c<<<516, 256, 0, stream>>>(Wc_st, fuse_b, bc, b_all);
  // [Wt2; Wi2] = Wc @ fuse_w
  gemm_nt_small<<<dim3(16,8,1), 256, 0, stream>>>(Wc_st, fuse_wT, W_all + DD,
                                                  2048, 1024, 1024, 0, 0, 0);
  // main: C = s @ W_all.T + b_all, scatter into d_out
  gemm_main<<<dim3(768), 512, 0, stream>>>(s_bf, W_all, out, b_all, 16384, 3072, 1024);
}

// Round 5
// 242.502 us; speedup vs baseline: 1.8398x; 1.8398x over previous
//
#include <hip/hip_runtime.h>
#include <stdint.h>

typedef float f32x4 __attribute__((ext_vector_type(4)));
typedef short s16x8 __attribute__((ext_vector_type(8)));
typedef short s16x4 __attribute__((ext_vector_type(4)));

__device__ __forceinline__ short f2bf(float f){
  union { float f; unsigned u; } v; v.f = f;
  unsigned r = v.u + 0x7FFFu + ((v.u >> 16) & 1u);
  return (short)(r >> 16);
}
__device__ __forceinline__ float bf2f(short h){
  union { unsigned u; float f; } v; v.u = ((unsigned)(unsigned short)h) << 16;
  return v.f;
}

// ---------- elementwise: o = bf16(a+b), 8 elems/thread ----------
__global__ void k_addcvt(const float* __restrict__ a, const float* __restrict__ b,
                         short* __restrict__ o){
  long i = (long)blockIdx.x * blockDim.x + threadIdx.x;
  const f32x4* a4 = (const f32x4*)a;
  const f32x4* b4 = (const f32x4*)b;
  f32x4 x0 = a4[2*i], x1 = a4[2*i+1];
  f32x4 y0 = b4[2*i], y1 = b4[2*i+1];
  s16x8 r;
  #pragma unroll
  for (int j=0;j<4;j++){ r[j] = f2bf(x0[j]+y0[j]); r[j+4] = f2bf(x1[j]+y1[j]); }
  *(s16x8*)(o + i*8) = r;
}

// ---------- fused prep: cvt x3 (blocks 0..3071), transcvt x3 (3072..6143),
// bias1 (6144..6655) ----------
__global__ void k_prep(const float* __restrict__ c0s, short* __restrict__ c0d,
                       const float* __restrict__ c1s, short* __restrict__ c1d,
                       const float* __restrict__ c2s, short* __restrict__ c2d,
                       const float* __restrict__ t0s, short* __restrict__ t0d,
                       const float* __restrict__ t1s, short* __restrict__ t1d,
                       const float* __restrict__ t2s, short* __restrict__ t2d,
                       const float* __restrict__ wt, const float* __restrict__ bvt, const float* __restrict__ obt,
                       const float* __restrict__ wi, const float* __restrict__ bvi, const float* __restrict__ obi,
                       float* __restrict__ bc){
  int bid = blockIdx.x;
  int tid = threadIdx.x;
  if (bid < 3072) {
    int z = bid >> 10, b = bid & 1023;
    const float* in = (z==0) ? c0s : ((z==1) ? c1s : c2s);
    short* out      = (z==0) ? c0d : ((z==1) ? c1d : c2d);
    long i = (long)b*256 + tid;
    f32x4 v = ((const f32x4*)in)[i];
    s16x4 r;
    #pragma unroll
    for (int j=0;j<4;j++) r[j] = f2bf(v[j]);
    *(s16x4*)(out + i*4) = r;
  } else if (bid < 6144) {
    int q = bid - 3072;
    int z = q >> 10, b = q & 1023;
    const float* in = (z==0) ? t0s : ((z==1) ? t1s : t2s);
    short* out      = (z==0) ? t0d : ((z==1) ? t1d : t2d);
    __shared__ float tile[32][33];
    int tx = tid & 31, ty = tid >> 5;
    int c0 = (b & 31)*32, r0 = (b >> 5)*32;
    #pragma unroll
    for (int i=ty; i<32; i+=8)
      tile[i][tx] = in[(long)(r0+i)*1024 + c0 + tx];
    __syncthreads();
    #pragma unroll
    for (int i=ty; i<32; i+=8)
      out[(long)(c0+i)*1024 + r0 + tx] = f2bf(tile[tx][i]);
  } else {
    int q = bid - 6144;
    int z = q >> 8, b = q & 255;
    const float* w  = z ? wi  : wt;
    const float* bv = z ? bvi : bvt;
    const float* ob = z ? obi : obt;
    int n = b*4 + (tid>>6);
    int lane = tid & 63;
    const float* row = w + (long)n*1024;
    float acc = 0.f;
    for (int j=lane; j<1024; j+=64) acc += row[j]*bv[j];
    #pragma unroll
    for (int m=32;m;m>>=1) acc += __shfl_xor(acc, m, 64);
    if (lane==0) bc[z*1024+n] = acc + ob[n];
  }
}

// ---------- bias2 + fuse_b copy folded in ----------
__global__ void k_bias2c(const short* __restrict__ Wc, const float* __restrict__ fuse_b,
                         const float* __restrict__ bc, float* __restrict__ b_all){
  if (blockIdx.x >= 512) {
    int i = (blockIdx.x - 512)*256 + threadIdx.x;
    b_all[i] = fuse_b[i];
    return;
  }
  int n = blockIdx.x*4 + (threadIdx.x>>6);
  int lane = threadIdx.x & 63;
  const short* row = Wc + (long)n*1024;
  float acc = 0.f;
  for (int j=lane; j<1024; j+=64) acc += bf2f(row[j])*fuse_b[j];
  #pragma unroll
  for (int m=32;m;m>>=1) acc += __shfl_xor(acc, m, 64);
  if (lane==0) b_all[1024+n] = acc + bc[n];
}

#define GLDS(src, dst) __builtin_amdgcn_global_load_lds( \
    (const __attribute__((address_space(1))) void*)(src), \
    (__attribute__((address_space(3))) void*)(dst), 16, 0, 0)

// ---------- small NT GEMM (128x128 tile, m97 structure): C bf16 = A@B^T ----------
__global__ __launch_bounds__(256, 2)
void gemm_nt_small(const short* __restrict__ Abase, const short* __restrict__ Bbase,
                   short* __restrict__ Cbase,
                   int M, int N, int K, long zA, long zB, long zC)
{
  __shared__ __align__(16) short ldsA[128*32];
  __shared__ __align__(16) short ldsB[128*32];
  const short* A = Abase + (long)blockIdx.z * zA;
  const short* B = Bbase + (long)blockIdx.z * zB;
  const int m0 = blockIdx.x * 128;
  const int n0 = blockIdx.y * 128;
  const int tid = threadIdx.x;
  const int lane = tid & 63;
  const int wv = tid >> 6;
  const int wm = wv >> 1, wn = wv & 1;

  f32x4 acc[4][4];
  #pragma unroll
  for (int i=0;i<4;i++)
    #pragma unroll
    for (int j=0;j<4;j++) acc[i][j] = (f32x4){0.f,0.f,0.f,0.f};

  const int bo0 = wv*1024 + lane*16;
  const int bo1 = bo0 + 4096;
  const int r0 = bo0 >> 6, c0 = bo0 & 63;
  const int r1 = bo1 >> 6, c1 = bo1 & 63;
  const long rsb = (long)K * 2;

  const char* Ab = (const char*)A;
  const char* Bb = (const char*)B;
  char* lA = (char*)&ldsA[0];
  char* lB = (char*)&ldsB[0];

  const int nkt = K >> 5;
  for (int kt = 0; kt < nkt; ++kt) {
    const long kb = (long)kt * 64;
    GLDS(Ab + (long)(m0 + r0)*rsb + kb + c0, lA + wv*1024);
    GLDS(Ab + (long)(m0 + r1)*rsb + kb + c1, lA + 4096 + wv*1024);
    GLDS(Bb + (long)(n0 + r0)*rsb + kb + c0, lB + wv*1024);
    GLDS(Bb + (long)(n0 + r1)*rsb + kb + c1, lB + 4096 + wv*1024);
    __syncthreads();

    s16x8 af[4], bfv[4];
    #pragma unroll
    for (int i=0;i<4;i++)
      af[i] = *(const s16x8*)(lA + (wm*64 + i*16 + (lane&15))*64 + (lane>>4)*16);
    #pragma unroll
    for (int j=0;j<4;j++)
      bfv[j] = *(const s16x8*)(lB + (wn*64 + j*16 + (lane&15))*64 + (lane>>4)*16);

    #pragma unroll
    for (int i=0;i<4;i++)
      #pragma unroll
      for (int j=0;j<4;j++)
        acc[i][j] = __builtin_amdgcn_mfma_f32_16x16x32_bf16(af[i], bfv[j], acc[i][j], 0, 0, 0);
    __syncthreads();
  }

  short* C = Cbase + (long)blockIdx.z * zC;
  #pragma unroll
  for (int j=0;j<4;j++){
    int gn = n0 + wn*64 + j*16 + (lane&15);
    #pragma unroll
    for (int i=0;i<4;i++){
      int gmb = m0 + wm*64 + i*16 + ((lane>>4)*4);
      #pragma unroll
      for (int r=0;r<4;r++)
        C[(long)(gmb+r)*N + gn] = f2bf(acc[i][j][r]);
    }
  }
}

// =================== main GEMM shared pieces ===================
#define MFMA16 __builtin_amdgcn_mfma_f32_16x16x32_bf16
#define VMW4 asm volatile("s_waitcnt vmcnt(4)" ::: "memory")
#define VMW0 asm volatile("s_waitcnt vmcnt(0)" ::: "memory")
#define NOP ((void)0)

// Common setup: tile coords (bid_off makes 3 slices of the 768-tile grid),
// acc init, stage-source precompute (inverse swizzle), lambdas.
#define GEMM_SETUP \
  const int nbn = N >> 8; \
  int bidf = blockIdx.x + bid_off; \
  int swz = (bidf & 7) * 96 + (bidf >> 3); \
  const int m0 = (swz / nbn) << 8; \
  const int n0 = (swz % nbn) << 8; \
  const int tid  = threadIdx.x; \
  const int lane = tid & 63; \
  const int wid  = tid >> 6; \
  const int wm   = wid >> 2; \
  const int wn   = wid & 3; \
  const long rsb = (long)K * 2; \
  const char* Ab = (const char*)A; \
  const char* Bb = (const char*)B; \
  f32x4 acc[8][4]; \
  _Pragma("unroll") \
  for (int i=0;i<8;i++) \
    _Pragma("unroll") \
    for (int j=0;j<4;j++) acc[i][j] = (f32x4){0.f,0.f,0.f,0.f}; \
  long srow[2][2]; int scol[2][2]; int sdst[2][2]; \
  _Pragma("unroll") \
  for (int H=0;H<2;H++) \
    _Pragma("unroll") \
    for (int sb=0;sb<2;sb++){ \
      int c = H*1024 + sb*512 + wid*64 + lane; \
      int q = c ^ ((c>>3)&7); \
      srow[H][sb] = (long)(q >> 3); \
      scol[H][sb] = (q & 7) << 4; \
      sdst[H][sb] = (H*1024 + sb*512 + wid*64) << 4; \
    } \
  auto stage = [&](const char* P, int tr0, int s, int RB, int H){ \
    const long ktb = (long)s << 7; \
    GLDS(P + ((long)tr0 + srow[H][0])*rsb + ktb + scol[H][0], lds + RB + sdst[H][0]); \
    GLDS(P + ((long)tr0 + srow[H][1])*rsb + ktb + scol[H][1], lds + RB + sdst[H][1]); \
  }; \
  const int swx = (lane & 7) << 4; \
  auto ldA = [&](int buf, int i, int ks) -> s16x8 { \
    int off = (wm*128 + i*16 + (lane&15))*128 + ks*64 + ((lane>>4)<<4); \
    off ^= swx; \
    return *(const s16x8*)(lds + (buf<<15) + off); \
  }; \
  auto ldB = [&](int buf, int j, int ks) -> s16x8 { \
    int off = (wn*64 + j*16 + (lane&15))*128 + ks*64 + ((lane>>4)<<4); \
    off ^= swx; \
    return *(const s16x8*)(lds + 65536 + (buf<<15) + off); \
  };

#define GEMM_EPILOGUE \
  const long BD = (long)M * 1024L; \
  _Pragma("unroll") \
  for (int j=0;j<4;j++){ \
    int gn = n0 + wn*64 + j*16 + (lane&15); \
    float bb = bias[gn]; \
    int region = gn >> 10; \
    long rbase = (region==0) ? 2*BD : ((region==1) ? 0L : BD); \
    int col = gn & 1023; \
    _Pragma("unroll") \
    for (int i=0;i<8;i++){ \
      int gr = m0 + wm*128 + i*16 + ((lane>>4)<<2); \
      _Pragma("unroll") \
      for (int r=0;r<4;r++) \
        O[rbase + (long)(gr+r)*1024 + col] = acc[i][j][r] + bb; \
    } \
  }

// ---- v0 phase macro: same-phase frag reads, lgkmcnt(0), setprio (R3 exact) ----
#define PH_V0(BUF, Q, STAGE_STMT, VM, PRIO) { \
  if ((Q)==0) { \
    _Pragma("unroll") \
    for (int j=0;j<4;j++){ bfr[j][0]=ldB(BUF,j,0); bfr[j][1]=ldB(BUF,j,1);} \
  } \
  s16x8 aq0 = ldA(BUF, 2*(Q), 0),   aq1 = ldA(BUF, 2*(Q), 1); \
  s16x8 aq2 = ldA(BUF, 2*(Q)+1, 0), aq3 = ldA(BUF, 2*(Q)+1, 1); \
  STAGE_STMT; \
  VM; \
  asm volatile("" ::: "memory"); \
  __builtin_amdgcn_s_barrier(); \
  asm volatile("s_waitcnt lgkmcnt(0)" ::: "memory"); \
  if (PRIO) __builtin_amdgcn_s_setprio(1); \
  _Pragma("unroll") \
  for (int j=0;j<4;j++){ \
    acc[2*(Q)][j]   = MFMA16(aq0, bfr[j][0], acc[2*(Q)][j],   0,0,0); \
    acc[2*(Q)][j]   = MFMA16(aq1, bfr[j][1], acc[2*(Q)][j],   0,0,0); \
    acc[2*(Q)+1][j] = MFMA16(aq2, bfr[j][0], acc[2*(Q)+1][j], 0,0,0); \
    acc[2*(Q)+1][j] = MFMA16(aq3, bfr[j][1], acc[2*(Q)+1][j], 0,0,0); \
  } \
  if (PRIO) __builtin_amdgcn_s_setprio(0); \
  asm volatile("" ::: "memory"); \
  __builtin_amdgcn_s_barrier(); \
}

#define V0_BODY(PRIO) \
  GEMM_SETUP \
  s16x8 bfr[4][2]; \
  const int nkt = K >> 6; \
  stage(Ab, m0, 0, 0,     0); stage(Ab, m0, 0, 0,     1); \
  stage(Bb, n0, 0, 65536, 0); stage(Bb, n0, 0, 65536, 1); \
  stage(Bb, n0, 1, 98304, 0); stage(Bb, n0, 1, 98304, 1); \
  VMW4; \
  asm volatile("" ::: "memory"); \
  __builtin_amdgcn_s_barrier(); \
  for (int it = 0; it < (nkt>>1) - 1; ++it) { \
    const int t = it*2; \
    PH_V0(0, 0, stage(Ab, m0, t+1, 32768, 0), NOP, PRIO) \
    PH_V0(0, 1, (stage(Ab, m0, t+1, 32768, 1), stage(Bb, n0, t+2, 65536, 0)), NOP, PRIO) \
    PH_V0(0, 2, stage(Bb, n0, t+2, 65536, 1), NOP, PRIO) \
    PH_V0(0, 3, NOP, VMW4, PRIO) \
    PH_V0(1, 0, stage(Ab, m0, t+2, 0, 0), NOP, PRIO) \
    PH_V0(1, 1, (stage(Ab, m0, t+2, 0, 1), stage(Bb, n0, t+3, 98304, 0)), NOP, PRIO) \
    PH_V0(1, 2, stage(Bb, n0, t+3, 98304, 1), NOP, PRIO) \
    PH_V0(1, 3, NOP, VMW4, PRIO) \
  } \
  { \
    PH_V0(0, 0, stage(Ab, m0, nkt-1, 32768, 0), NOP, PRIO) \
    PH_V0(0, 1, stage(Ab, m0, nkt-1, 32768, 1), NOP, PRIO) \
    PH_V0(0, 2, NOP, NOP, PRIO) \
    PH_V0(0, 3, NOP, VMW0, PRIO) \
    PH_V0(1, 0, NOP, NOP, PRIO) \
    PH_V0(1, 1, NOP, NOP, PRIO) \
    PH_V0(1, 2, NOP, NOP, PRIO) \
    PH_V0(1, 3, NOP, NOP, PRIO) \
  } \
  GEMM_EPILOGUE

// v0: R3 control (same-phase reads, lgkmcnt0, setprio)
__global__ __launch_bounds__(512, 2)
void gemm_v0(const short* __restrict__ A, const short* __restrict__ B,
             float* __restrict__ O, const float* __restrict__ bias,
             int M, int N, int K, int bid_off)
{
  __shared__ __align__(16) char lds[131072];
  V0_BODY(1)
}

// v3: v0 minus setprio
__global__ __launch_bounds__(512, 2)
void gemm_v3(const short* __restrict__ A, const short* __restrict__ B,
             float* __restrict__ O, const float* __restrict__ bias,
             int M, int N, int K, int bid_off)
{
  __shared__ __align__(16) char lds[131072];
  V0_BODY(0)
}

// ---- v2: A-frags pipelined one phase ahead (ping-pong afP/afQ), single B bank,
// no explicit lgkm waits (compiler emits counted per-register waits). ----
#define LDBF_V2(B) { _Pragma("unroll") for (int j=0;j<4;j++){ bfr[j][0]=ldB(B,j,0); bfr[j][1]=ldB(B,j,1);} }

#define PH_V2(ACC0, AC, AN, NBUF, NQ, LDBF_STMT, STAGE_STMT, VM) { \
  LDBF_STMT; \
  AN[0] = ldA(NBUF, 2*(NQ),   0); \
  AN[1] = ldA(NBUF, 2*(NQ),   1); \
  AN[2] = ldA(NBUF, 2*(NQ)+1, 0); \
  AN[3] = ldA(NBUF, 2*(NQ)+1, 1); \
  STAGE_STMT; \
  VM; \
  asm volatile("" ::: "memory"); \
  __builtin_amdgcn_s_barrier(); \
  __builtin_amdgcn_s_setprio(1); \
  _Pragma("unroll") \
  for (int j=0;j<4;j++){ \
    acc[(ACC0)][j]   = MFMA16(AC[0], bfr[j][0], acc[(ACC0)][j],   0,0,0); \
    acc[(ACC0)][j]   = MFMA16(AC[1], bfr[j][1], acc[(ACC0)][j],   0,0,0); \
    acc[(ACC0)+1][j] = MFMA16(AC[2], bfr[j][0], acc[(ACC0)+1][j], 0,0,0); \
    acc[(ACC0)+1][j] = MFMA16(AC[3], bfr[j][1], acc[(ACC0)+1][j], 0,0,0); \
  } \
  __builtin_amdgcn_s_setprio(0); \
  asm volatile("" ::: "memory"); \
  __builtin_amdgcn_s_barrier(); \
}

__global__ __launch_bounds__(512, 2)
void gemm_v2(const short* __restrict__ A, const short* __restrict__ B,
             float* __restrict__ O, const float* __restrict__ bias,
             int M, int N, int K, int bid_off)
{
  __shared__ __align__(16) char lds[131072];
  GEMM_SETUP
  s16x8 bfr[4][2];
  s16x8 afP[4], afQ[4];
  const int nkt = K >> 6;

  // Prologue: A(0)->A0, B(0)->B0, B(1)->B1; drain to 4 (B1 stays in flight).
  stage(Ab, m0, 0, 0,     0); stage(Ab, m0, 0, 0,     1);
  stage(Bb, n0, 0, 65536, 0); stage(Bb, n0, 0, 65536, 1);
  stage(Bb, n0, 1, 98304, 0); stage(Bb, n0, 1, 98304, 1);
  VMW4;
  asm volatile("" ::: "memory");
  __builtin_amdgcn_s_barrier();
  // Preload A-frags for ph1's compute (buf0, Q0). bfr loaded in ph1 itself.
  afP[0]=ldA(0,0,0); afP[1]=ldA(0,0,1); afP[2]=ldA(0,1,0); afP[3]=ldA(0,1,1);

  for (int it = 0; it < (nkt>>1) - 1; ++it) {
    const int t = it*2;
    // ph1: compute (0,Q0); read (0,Q1); LDBF(0) for this phase
    PH_V2(0, afP, afQ, 0, 1, LDBF_V2(0), stage(Ab, m0, t+1, 32768, 0), NOP)
    // ph2: compute (0,Q1); read (0,Q2)
    PH_V2(2, afQ, afP, 0, 2, NOP, (stage(Ab, m0, t+1, 32768, 1), stage(Bb, n0, t+2, 65536, 0)), NOP)
    // ph3: compute (0,Q2); read (0,Q3); VMW4 drains A(t+1),B(t+1-prev); leaves B(t+2)
    PH_V2(4, afP, afQ, 0, 3, NOP, stage(Bb, n0, t+2, 65536, 1), VMW4)
    // ph4: compute (0,Q3); read (1,Q0)  [A-buf1 valid since ph3 VMW4+barrier]
    PH_V2(6, afQ, afP, 1, 0, NOP, NOP, NOP)
    // ph5: compute (1,Q0); read (1,Q1); LDBF(1) [B-buf1 drained at ph3]
    PH_V2(0, afP, afQ, 1, 1, LDBF_V2(1), stage(Ab, m0, t+2, 0, 0), NOP)
    // ph6: compute (1,Q1); read (1,Q2)
    PH_V2(2, afQ, afP, 1, 2, NOP, (stage(Ab, m0, t+2, 0, 1), stage(Bb, n0, t+3, 98304, 0)), NOP)
    // ph7: compute (1,Q2); read (1,Q3); VMW4 drains A(t+2),B(t+2); leaves B(t+3)
    PH_V2(4, afP, afQ, 1, 3, NOP, stage(Bb, n0, t+3, 98304, 1), VMW4)
    // ph8: compute (1,Q3); read (0,Q0) of t+2 [A-buf0 drained at ph7]
    PH_V2(6, afQ, afP, 0, 0, NOP, NOP, NOP)
  }
  {
    // Final iter (t = nkt-2): stage only A(nkt-1); VMW0 at ph3; ph8 reads dead.
    PH_V2(0, afP, afQ, 0, 1, LDBF_V2(0), stage(Ab, m0, nkt-1, 32768, 0), NOP)
    PH_V2(2, afQ, afP, 0, 2, NOP, stage(Ab, m0, nkt-1, 32768, 1), NOP)
    PH_V2(4, afP, afQ, 0, 3, NOP, NOP, VMW0)
    PH_V2(6, afQ, afP, 1, 0, NOP, NOP, NOP)
    PH_V2(0, afP, afQ, 1, 1, LDBF_V2(1), NOP, NOP)
    PH_V2(2, afQ, afP, 1, 2, NOP, NOP, NOP)
    PH_V2(4, afP, afQ, 1, 3, NOP, NOP, NOP)
    PH_V2(6, afQ, afP, 0, 0, NOP, NOP, NOP)
  }
  GEMM_EPILOGUE
}

extern "C" void kernel_launch(void* const* d_in, const int* in_sizes, int n_in,
                              void* d_out, int out_size, void* d_ws, size_t ws_size,
                              hipStream_t stream) {
  const float* text    = (const float*)d_in[0];
  const float* image   = (const float*)d_in[1];
  const float* fuse_w  = (const float*)d_in[2];
  const float* fuse_b  = (const float*)d_in[3];
  const float* t_in_w  = (const float*)d_in[4];
  const float* t_in_b  = (const float*)d_in[5];
  const float* t_out_w = (const float*)d_in[6];
  const float* t_out_b = (const float*)d_in[7];
  const float* i_in_w  = (const float*)d_in[8];
  const float* i_in_b  = (const float*)d_in[9];
  const float* i_out_w = (const float*)d_in[10];
  const float* i_out_b = (const float*)d_in[11];
  float* out = (float*)d_out;

  const long DD = 1024L*1024L;
  char* ws = (char*)d_ws;
  short* s_bf    = (short*)ws; ws += 16384L*1024*2;
  short* W_all   = (short*)ws; ws += 3*DD*2;      // rows: [fuse_w; Wt2; Wi2]
  short* wvT     = (short*)ws; ws += 2*DD*2;      // [wvT_t; wvT_i]
  short* fuse_wT = (short*)ws; ws += DD*2;
  short* outw_st = (short*)ws; ws += 2*DD*2;      // [t_out_w; i_out_w] bf16
  short* Wc_st   = (short*)ws; ws += 2*DD*2;      // [Wc_t; Wc_i]
  float* bc      = (float*)ws; ws += 2048*4;
  float* b_all   = (float*)ws; ws += 3072*4;

  // prep
  k_addcvt<<<8192, 256, 0, stream>>>(text, image, s_bf);
  k_prep<<<6656, 256, 0, stream>>>(fuse_w, W_all,
                                   t_out_w, outw_st,
                                   i_out_w, outw_st + DD,
                                   t_in_w + 2*DD, wvT,
                                   i_in_w + 2*DD, wvT + DD,
                                   fuse_w, fuse_wT,
                                   t_out_w, t_in_b + 2048, t_out_b,
                                   i_out_w, i_in_b + 2048, i_out_b, bc);

  // Wc_z = out_w_z @ wv_z
  gemm_nt_small<<<dim3(8,8,2), 256, 0, stream>>>(outw_st, wvT, Wc_st,
                                                 1024, 1024, 1024, DD, DD, DD);
  // b_all[1024..3072) = Wc @ fuse_b + bc ; b_all[0..1024) = fuse_b
  k_bias2c<<<516, 256, 0, stream>>>(Wc_st, fuse_b, bc, b_all);
  // [Wt2; Wi2] = Wc @ fuse_w
  gemm_nt_small<<<dim3(16,8,1), 256, 0, stream>>>(Wc_st, fuse_wT, W_all + DD,
                                                  2048, 1024, 1024, 0, 0, 0);

  // main GEMM: within-probe A/B — three slices (256 tiles each, 1 block-wave),
  // union covers all 768 tiles; all write the same d_out layout.
  gemm_v0<<<256, 512, 0, stream>>>(s_bf, W_all, out, b_all, 16384, 3072, 1024, 0);
  gemm_v2<<<256, 512, 0, stream>>>(s_bf, W_all, out, b_all, 16384, 3072, 1024, 256);
  gemm_v3<<<256, 512, 0, stream>>>(s_bf, W_all, out, b_all, 16384, 3072, 1024, 512);
}

// Round 7
// 227.095 us; speedup vs baseline: 1.9646x; 1.0678x over previous
//
#include <hip/hip_runtime.h>
#include <stdint.h>

typedef float f32x4 __attribute__((ext_vector_type(4)));
typedef short s16x8 __attribute__((ext_vector_type(8)));
typedef short s16x4 __attribute__((ext_vector_type(4)));

__device__ __forceinline__ short f2bf(float f){
  union { float f; unsigned u; } v; v.f = f;
  unsigned r = v.u + 0x7FFFu + ((v.u >> 16) & 1u);
  return (short)(r >> 16);
}
__device__ __forceinline__ float bf2f(short h){
  union { unsigned u; float f; } v; v.u = ((unsigned)(unsigned short)h) << 16;
  return v.f;
}

// ---------- elementwise: o = bf16(a+b), 8 elems/thread ----------
__global__ void k_addcvt(const float* __restrict__ a, const float* __restrict__ b,
                         short* __restrict__ o){
  long i = (long)blockIdx.x * blockDim.x + threadIdx.x;
  const f32x4* a4 = (const f32x4*)a;
  const f32x4* b4 = (const f32x4*)b;
  f32x4 x0 = a4[2*i], x1 = a4[2*i+1];
  f32x4 y0 = b4[2*i], y1 = b4[2*i+1];
  s16x8 r;
  #pragma unroll
  for (int j=0;j<4;j++){ r[j] = f2bf(x0[j]+y0[j]); r[j+4] = f2bf(x1[j]+y1[j]); }
  *(s16x8*)(o + i*8) = r;
}

// ---------- fused prep: cvt x3 (blocks 0..3071), transcvt x3 (3072..6143),
// bias1 (6144..6655) ----------
__global__ void k_prep(const float* __restrict__ c0s, short* __restrict__ c0d,
                       const float* __restrict__ c1s, short* __restrict__ c1d,
                       const float* __restrict__ c2s, short* __restrict__ c2d,
                       const float* __restrict__ t0s, short* __restrict__ t0d,
                       const float* __restrict__ t1s, short* __restrict__ t1d,
                       const float* __restrict__ t2s, short* __restrict__ t2d,
                       const float* __restrict__ wt, const float* __restrict__ bvt, const float* __restrict__ obt,
                       const float* __restrict__ wi, const float* __restrict__ bvi, const float* __restrict__ obi,
                       float* __restrict__ bc){
  int bid = blockIdx.x;
  int tid = threadIdx.x;
  if (bid < 3072) {
    int z = bid >> 10, b = bid & 1023;
    const float* in = (z==0) ? c0s : ((z==1) ? c1s : c2s);
    short* out      = (z==0) ? c0d : ((z==1) ? c1d : c2d);
    long i = (long)b*256 + tid;
    f32x4 v = ((const f32x4*)in)[i];
    s16x4 r;
    #pragma unroll
    for (int j=0;j<4;j++) r[j] = f2bf(v[j]);
    *(s16x4*)(out + i*4) = r;
  } else if (bid < 6144) {
    int q = bid - 3072;
    int z = q >> 10, b = q & 1023;
    const float* in = (z==0) ? t0s : ((z==1) ? t1s : t2s);
    short* out      = (z==0) ? t0d : ((z==1) ? t1d : t2d);
    __shared__ float tile[32][33];
    int tx = tid & 31, ty = tid >> 5;
    int c0 = (b & 31)*32, r0 = (b >> 5)*32;
    #pragma unroll
    for (int i=ty; i<32; i+=8)
      tile[i][tx] = in[(long)(r0+i)*1024 + c0 + tx];
    __syncthreads();
    #pragma unroll
    for (int i=ty; i<32; i+=8)
      out[(long)(c0+i)*1024 + r0 + tx] = f2bf(tile[tx][i]);
  } else {
    int q = bid - 6144;
    int z = q >> 8, b = q & 255;
    const float* w  = z ? wi  : wt;
    const float* bv = z ? bvi : bvt;
    const float* ob = z ? obi : obt;
    int n = b*4 + (tid>>6);
    int lane = tid & 63;
    const float* row = w + (long)n*1024;
    float acc = 0.f;
    for (int j=lane; j<1024; j+=64) acc += row[j]*bv[j];
    #pragma unroll
    for (int m=32;m;m>>=1) acc += __shfl_xor(acc, m, 64);
    if (lane==0) bc[z*1024+n] = acc + ob[n];
  }
}

// ---------- bias2 + fuse_b copy folded in ----------
__global__ void k_bias2c(const short* __restrict__ Wc, const float* __restrict__ fuse_b,
                         const float* __restrict__ bc, float* __restrict__ b_all){
  if (blockIdx.x >= 512) {
    int i = (blockIdx.x - 512)*256 + threadIdx.x;
    b_all[i] = fuse_b[i];
    return;
  }
  int n = blockIdx.x*4 + (threadIdx.x>>6);
  int lane = threadIdx.x & 63;
  const short* row = Wc + (long)n*1024;
  float acc = 0.f;
  for (int j=lane; j<1024; j+=64) acc += bf2f(row[j])*fuse_b[j];
  #pragma unroll
  for (int m=32;m;m>>=1) acc += __shfl_xor(acc, m, 64);
  if (lane==0) b_all[1024+n] = acc + bc[n];
}

#define GLDS(src, dst) __builtin_amdgcn_global_load_lds( \
    (const __attribute__((address_space(1))) void*)(src), \
    (__attribute__((address_space(3))) void*)(dst), 16, 0, 0)

// ---------- small NT GEMM (128x128 tile, m97 structure): C bf16 = A@B^T ----------
__global__ __launch_bounds__(256, 2)
void gemm_nt_small(const short* __restrict__ Abase, const short* __restrict__ Bbase,
                   short* __restrict__ Cbase,
                   int M, int N, int K, long zA, long zB, long zC)
{
  __shared__ __align__(16) short ldsA[128*32];
  __shared__ __align__(16) short ldsB[128*32];
  const short* A = Abase + (long)blockIdx.z * zA;
  const short* B = Bbase + (long)blockIdx.z * zB;
  const int m0 = blockIdx.x * 128;
  const int n0 = blockIdx.y * 128;
  const int tid = threadIdx.x;
  const int lane = tid & 63;
  const int wv = tid >> 6;
  const int wm = wv >> 1, wn = wv & 1;

  f32x4 acc[4][4];
  #pragma unroll
  for (int i=0;i<4;i++)
    #pragma unroll
    for (int j=0;j<4;j++) acc[i][j] = (f32x4){0.f,0.f,0.f,0.f};

  const int bo0 = wv*1024 + lane*16;
  const int bo1 = bo0 + 4096;
  const int r0 = bo0 >> 6, c0 = bo0 & 63;
  const int r1 = bo1 >> 6, c1 = bo1 & 63;
  const long rsb = (long)K * 2;

  const char* Ab = (const char*)A;
  const char* Bb = (const char*)B;
  char* lA = (char*)&ldsA[0];
  char* lB = (char*)&ldsB[0];

  const int nkt = K >> 5;
  for (int kt = 0; kt < nkt; ++kt) {
    const long kb = (long)kt * 64;
    GLDS(Ab + (long)(m0 + r0)*rsb + kb + c0, lA + wv*1024);
    GLDS(Ab + (long)(m0 + r1)*rsb + kb + c1, lA + 4096 + wv*1024);
    GLDS(Bb + (long)(n0 + r0)*rsb + kb + c0, lB + wv*1024);
    GLDS(Bb + (long)(n0 + r1)*rsb + kb + c1, lB + 4096 + wv*1024);
    __syncthreads();

    s16x8 af[4], bfv[4];
    #pragma unroll
    for (int i=0;i<4;i++)
      af[i] = *(const s16x8*)(lA + (wm*64 + i*16 + (lane&15))*64 + (lane>>4)*16);
    #pragma unroll
    for (int j=0;j<4;j++)
      bfv[j] = *(const s16x8*)(lB + (wn*64 + j*16 + (lane&15))*64 + (lane>>4)*16);

    #pragma unroll
    for (int i=0;i<4;i++)
      #pragma unroll
      for (int j=0;j<4;j++)
        acc[i][j] = __builtin_amdgcn_mfma_f32_16x16x32_bf16(af[i], bfv[j], acc[i][j], 0, 0, 0);
    __syncthreads();
  }

  short* C = Cbase + (long)blockIdx.z * zC;
  #pragma unroll
  for (int j=0;j<4;j++){
    int gn = n0 + wn*64 + j*16 + (lane&15);
    #pragma unroll
    for (int i=0;i<4;i++){
      int gmb = m0 + wm*64 + i*16 + ((lane>>4)*4);
      #pragma unroll
      for (int r=0;r<4;r++)
        C[(long)(gmb+r)*N + gn] = f2bf(acc[i][j][r]);
    }
  }
}

// ---------- main NT GEMM: 256x256, BK=64, 2 phases per K-tile, 1 barrier/phase ----------
// LDS: Abuf0 @0, Abuf1 @32768, Bbuf0 @65536, Bbuf1 @98304 (32 KB each).
// Swizzle: 16B-chunk s of row r stored at s^(r&7); conflict-free (R3: 0 conflicts).
// Phase = [ds_reads | VMW | s_barrier | stage-issue | lgkm0 | 32 MFMA].
//   ks0 phase of tile t: read ALL B-frags (8) + A-ks0 (8); stage A(t+1)->Abuf[(t+1)&1]. VMW4.
//   ks1 phase of tile t: read A-ks1 (8);                   stage B(t+2)->Bbuf[t&1].   VMW0.
// Queue trace (units of 4 loads): entry P(t,0): [B(t+1)]; VMW4 no-op; +A(t+1).
//   P(t,1): VMW0 drains B(t+1)+A(t+1); +B(t+2). So at P(t+1,0) reads, A(t+1) and
//   B(t+1) are drained AND fenced by P(t,1)'s barrier (vmcnt is per-wave; drain
//   happens before the barrier every wave passes). R6's bug: VMW4 here left
//   A(t+1) in flight at its first read.
// Write-side: each stage targets a buffer whose last reads completed before the
// stage's preceding barrier (reads complete at that wave's pre-MFMA lgkm0 one
// phase earlier; barrier orders it for all waves).
#define MFMA16 __builtin_amdgcn_mfma_f32_16x16x32_bf16
#define VMW4 asm volatile("s_waitcnt vmcnt(4)" ::: "memory")
#define VMW0 asm volatile("s_waitcnt vmcnt(0)" ::: "memory")
#define LGKM0 asm volatile("s_waitcnt lgkmcnt(0)" ::: "memory")
#define MEMF asm volatile("" ::: "memory")

__global__ __launch_bounds__(512, 2)
void gemm_main(const short* __restrict__ A, const short* __restrict__ B,
               float* __restrict__ O, const float* __restrict__ bias,
               int M, int N, int K)
{
  __shared__ __align__(16) char lds[131072];

  const int nbn = N >> 8;
  const int nwg = (M >> 8) * nbn;
  const int cpx = nwg >> 3;
  int bid = blockIdx.x;
  int swz = (bid & 7) * cpx + (bid >> 3);
  const int m0 = (swz / nbn) << 8;
  const int n0 = (swz % nbn) << 8;

  const int tid  = threadIdx.x;
  const int lane = tid & 63;
  const int wid  = tid >> 6;
  const int wm   = wid >> 2;   // 0..1
  const int wn   = wid & 3;    // 0..3
  const long rsb = (long)K * 2;
  const char* Ab = (const char*)A;
  const char* Bb = (const char*)B;

  f32x4 acc[8][4];
  #pragma unroll
  for (int i=0;i<8;i++)
    #pragma unroll
    for (int j=0;j<4;j++) acc[i][j] = (f32x4){0.f,0.f,0.f,0.f};

  // Stage source precompute: linear LDS dest chunk c receives logical chunk
  // q = c ^ ((c>>3)&7)  (row preserved; inverse of the read swizzle).
  long srow[2][2]; int scol[2][2]; int sdst[2][2];
  #pragma unroll
  for (int H=0;H<2;H++)
    #pragma unroll
    for (int sb=0;sb<2;sb++){
      int c = H*1024 + sb*512 + wid*64 + lane;
      int q = c ^ ((c>>3)&7);
      srow[H][sb] = (long)(q >> 3);
      scol[H][sb] = (q & 7) << 4;
      sdst[H][sb] = (H*1024 + sb*512 + wid*64) << 4;
    }

  auto stage = [&](const char* P, int tr0, int s /*K-tile*/, int RB, int H){
    const long ktb = (long)s << 7;
    GLDS(P + ((long)tr0 + srow[H][0])*rsb + ktb + scol[H][0], lds + RB + sdst[H][0]);
    GLDS(P + ((long)tr0 + srow[H][1])*rsb + ktb + scol[H][1], lds + RB + sdst[H][1]);
  };

  const int swx = (lane & 7) << 4;   // read swizzle (row&7 == lane&7 for all frags)
  auto ldA = [&](int RB, int i, int ks) -> s16x8 {
    int off = (wm*128 + i*16 + (lane&15))*128 + ks*64 + ((lane>>4)<<4);
    off ^= swx;
    return *(const s16x8*)(lds + RB + off);
  };
  auto ldB = [&](int RB, int j, int ks) -> s16x8 {
    int off = (wn*64 + j*16 + (lane&15))*128 + ks*64 + ((lane>>4)<<4);
    off ^= swx;
    return *(const s16x8*)(lds + 65536 + RB + off);
  };

  s16x8 bfr[4][2];
  s16x8 af[8];
  const int nkt = K >> 6;  // 16 for K=1024

  // Prologue: A(0)->Abuf0, B(0)->Bbuf0, B(1)->Bbuf1; VMW4 drains A(0)+B(0)
  // (12 loads -> 4), leaves B(1)x4 in flight (drained at P(0,1) VMW0).
  stage(Ab, m0, 0, 0,     0); stage(Ab, m0, 0, 0,     1);
  stage(Bb, n0, 0, 65536, 0); stage(Bb, n0, 0, 65536, 1);
  stage(Bb, n0, 1, 98304, 0); stage(Bb, n0, 1, 98304, 1);
  VMW4; MEMF;
  __builtin_amdgcn_s_barrier();

  for (int t = 0; t < nkt; ++t) {
    const int RB = (t & 1) << 15;
    // -------- ks0 phase --------
    #pragma unroll
    for (int j=0;j<4;j++){ bfr[j][0] = ldB(RB, j, 0); bfr[j][1] = ldB(RB, j, 1); }
    #pragma unroll
    for (int i=0;i<8;i++) af[i] = ldA(RB, i, 0);
    VMW4; MEMF;
    __builtin_amdgcn_s_barrier();
    if (t+1 < nkt) {
      const int AB2 = ((t+1)&1) << 15;
      stage(Ab, m0, t+1, AB2, 0); stage(Ab, m0, t+1, AB2, 1);
    }
    LGKM0;
    __builtin_amdgcn_s_setprio(1);
    #pragma unroll
    for (int i=0;i<8;i++)
      #pragma unroll
      for (int j=0;j<4;j++)
        acc[i][j] = MFMA16(af[i], bfr[j][0], acc[i][j], 0, 0, 0);
    __builtin_amdgcn_s_setprio(0);
    // -------- ks1 phase --------
    #pragma unroll
    for (int i=0;i<8;i++) af[i] = ldA(RB, i, 1);
    VMW0; MEMF;            // drains B(t+1) AND A(t+1) before the barrier (R6 fix)
    __builtin_amdgcn_s_barrier();
    if (t+2 < nkt) {
      const int BB2 = 65536 + RB;   // Bbuf[t&1]: all its reads done at ks0
      stage(Bb, n0, t+2, BB2, 0); stage(Bb, n0, t+2, BB2, 1);
    }
    LGKM0;
    __builtin_amdgcn_s_setprio(1);
    #pragma unroll
    for (int i=0;i<8;i++)
      #pragma unroll
      for (int j=0;j<4;j++)
        acc[i][j] = MFMA16(af[i], bfr[j][1], acc[i][j], 0, 0, 0);
    __builtin_amdgcn_s_setprio(0);
  }

  // Epilogue: fp32 + bias, scatter by output region (text | image | fused).
  const long BD = (long)M * 1024L;
  #pragma unroll
  for (int j=0;j<4;j++){
    int gn = n0 + wn*64 + j*16 + (lane&15);
    float bb = bias[gn];
    int region = gn >> 10;
    long rbase = (region==0) ? 2*BD : ((region==1) ? 0L : BD);
    int col = gn & 1023;
    #pragma unroll
    for (int i=0;i<8;i++){
      int gr = m0 + wm*128 + i*16 + ((lane>>4)<<2);
      #pragma unroll
      for (int r=0;r<4;r++)
        O[rbase + (long)(gr+r)*1024 + col] = acc[i][j][r] + bb;
    }
  }
}

extern "C" void kernel_launch(void* const* d_in, const int* in_sizes, int n_in,
                              void* d_out, int out_size, void* d_ws, size_t ws_size,
                              hipStream_t stream) {
  const float* text    = (const float*)d_in[0];
  const float* image   = (const float*)d_in[1];
  const float* fuse_w  = (const float*)d_in[2];
  const float* fuse_b  = (const float*)d_in[3];
  const float* t_in_w  = (const float*)d_in[4];
  const float* t_in_b  = (const float*)d_in[5];
  const float* t_out_w = (const float*)d_in[6];
  const float* t_out_b = (const float*)d_in[7];
  const float* i_in_w  = (const float*)d_in[8];
  const float* i_in_b  = (const float*)d_in[9];
  const float* i_out_w = (const float*)d_in[10];
  const float* i_out_b = (const float*)d_in[11];
  float* out = (float*)d_out;

  const long DD = 1024L*1024L;
  char* ws = (char*)d_ws;
  short* s_bf    = (short*)ws; ws += 16384L*1024*2;
  short* W_all   = (short*)ws; ws += 3*DD*2;      // rows: [fuse_w; Wt2; Wi2]
  short* wvT     = (short*)ws; ws += 2*DD*2;      // [wvT_t; wvT_i]
  short* fuse_wT = (short*)ws; ws += DD*2;
  short* outw_st = (short*)ws; ws += 2*DD*2;      // [t_out_w; i_out_w] bf16
  short* Wc_st   = (short*)ws; ws += 2*DD*2;      // [Wc_t; Wc_i]
  float* bc      = (float*)ws; ws += 2048*4;
  float* b_all   = (float*)ws; ws += 3072*4;

  // prep
  k_addcvt<<<8192, 256, 0, stream>>>(text, image, s_bf);
  k_prep<<<6656, 256, 0, stream>>>(fuse_w, W_all,
                                   t_out_w, outw_st,
                                   i_out_w, outw_st + DD,
                                   t_in_w + 2*DD, wvT,
                                   i_in_w + 2*DD, wvT + DD,
                                   fuse_w, fuse_wT,
                                   t_out_w, t_in_b + 2048, t_out_b,
                                   i_out_w, i_in_b + 2048, i_out_b, bc);

  // Wc_z = out_w_z @ wv_z
  gemm_nt_small<<<dim3(8,8,2), 256, 0, stream>>>(outw_st, wvT, Wc_st,
                                                 1024, 1024, 1024, DD, DD, DD);
  // b_all[1024..3072) = Wc @ fuse_b + bc ; b_all[0..1024) = fuse_b
  k_bias2c<<<516, 256, 0, stream>>>(Wc_st, fuse_b, bc, b_all);
  // [Wt2; Wi2] = Wc @ fuse_w
  gemm_nt_small<<<dim3(16,8,1), 256, 0, stream>>>(Wc_st, fuse_wT, W_all + DD,
                                                  2048, 1024, 1024, 0, 0, 0);
  // main: C = s @ W_all.T + b_all, scatter into d_out
  gemm_main<<<dim3(768), 512, 0, stream>>>(s_bf, W_all, out, b_all, 16384, 3072, 1024);
}